// Round 11
// baseline (108776.111 us; speedup 1.0000x reference)
//
#include <hip/hip_runtime.h>

#define H 512
#define W4 4
#define RINGN 8
#define NWG 128
#define HS 4          // H / NWG
#define NTH 256

// ---------- helpers ----------
__device__ __forceinline__ float sigf(float x){ return 1.f/(1.f+__expf(-x)); }
__device__ __forceinline__ float tanhft(float x){
  float t = __expf(-2.f*fabsf(x));      // never overflows
  float r = (1.f - t)/(1.f + t);
  return copysignf(r, x);
}
// swizzled LDS element index for column-major weight slices
__device__ __forceinline__ int swz(int dd, int k){
  return (dd << 9) | ((((k >> 2) ^ (dd & 7)) << 2) | (k & 3));
}
__device__ __forceinline__ void st_rel(float* p, float v){
  __hip_atomic_store(p, v, __ATOMIC_RELEASE, __HIP_MEMORY_SCOPE_AGENT);
}
__device__ __forceinline__ float ld_acq(const float* p){
  return __hip_atomic_load(p, __ATOMIC_ACQUIRE, __HIP_MEMORY_SCOPE_AGENT);
}
__device__ __forceinline__ void fence_agent(){ __threadfence(); }

// ---------- persistent serial lattice scan (all projections in-kernel) ----------
struct SLds {
  float Wh_l [12*512];
  float Wwh_l[12*512];
  float Wi_l [12*512];
  float Wwi_l[12*512];
  float Ah_l [4*512];
  float Ai_l [4*512];
  float h_l [H];
  float x_l [H];
  float we_l[W4*520];          // wemb(j-1) rows, padded stride
  float wcf [W4*520];          // full wc(j-1), padded stride
  float gh_l[12];
  float wgh_l[12];
  float gx_l[12];
  float awi_l[HS];
  float wgp_l[W4][12];
  float bmi_l[12];
  float bw_l [12];
  float bal_l[HS];
  float ring_c_l  [RINGN][W4][HS];
  float ring_awh_l[RINGN][W4][HS];
  float c_prev_l[HS];
  int ring_len_l[RINGN][W4];
  int ring_step_l[RINGN];
  int klen_l[W4];
};

__global__ __launch_bounds__(NTH) void lattice_serial(
    const float* __restrict__ xg,  const float* __restrict__ kbe,
    const int*   __restrict__ kblen,
    const float* __restrict__ Wi,  const float* __restrict__ Wh,
    const float* __restrict__ bmi, const float* __restrict__ Ai,
    const float* __restrict__ Ah,  const float* __restrict__ bal,
    const float* __restrict__ Wwi, const float* __restrict__ Wwh,
    const float* __restrict__ bw,
    float* hbuf, float* wcbuf, int* flagA, int* flagC,
    float* __restrict__ out, int T)
{
  __shared__ SLds S;
  const int tid  = threadIdx.x;
  const int wg   = blockIdx.x;
  const int base = wg * HS;

  // ---- stage weight column slices (f32, swizzled) ----
  for (int i = tid; i < 12*512; i += NTH){
    int d = i >> 9, k = i & 511;
    size_t gcol = (size_t)(d >> 2)*512 + base + (d & 3);
    S.Wh_l [swz(d,k)] = Wh [(size_t)k*1536 + gcol];
    S.Wwh_l[swz(d,k)] = Wwh[(size_t)k*1536 + gcol];
    S.Wi_l [swz(d,k)] = Wi [(size_t)k*1536 + gcol];
    S.Wwi_l[swz(d,k)] = Wwi[(size_t)k*1536 + gcol];
  }
  for (int i = tid; i < 4*512; i += NTH){
    int c = i >> 9, k = i & 511;
    S.Ah_l[swz(c,k)] = Ah[(size_t)k*512 + base + c];
    S.Ai_l[swz(c,k)] = Ai[(size_t)k*512 + base + c];
  }
  if (tid < 12){
    int gcol = (tid >> 2)*512 + base + (tid & 3);
    S.bmi_l[tid] = bmi[gcol];
    S.bw_l [tid] = bw [gcol];
  }
  if (tid >= 16 && tid < 16+HS) S.bal_l[tid-16] = bal[base + tid - 16];
  for (int i = tid; i < H; i += NTH){ S.h_l[i] = 0.f; S.x_l[i] = 0.f; }
  for (int i = tid; i < W4*520; i += NTH) S.we_l[i] = 0.f;
  for (int i = tid; i < RINGN*W4*HS; i += NTH){
    ((float*)S.ring_c_l)[i]   = 0.f;
    ((float*)S.ring_awh_l)[i] = 0.f;
  }
  if (tid < RINGN) S.ring_step_l[tid] = -2*RINGN;
  if (tid < RINGN*W4) ((int*)S.ring_len_l)[tid] = 0;
  if (tid < HS) S.c_prev_l[tid] = 0.f;
  __syncthreads();

  for (int j = 0; j < T; ++j){
    // ---- register prefetch: x(j), wemb(j-1), klen(j-1) (independent of sync) ----
    float xv0 = xg[(size_t)j*H + tid];
    float xv1 = xg[(size_t)j*H + NTH + tid];
    float wv[8]; int pfi = 0;
    if (j > 0){
      #pragma unroll
      for (int r = 0; r < 8; ++r) wv[r] = kbe[(size_t)(j-1)*(W4*H) + r*NTH + tid];
      if (tid >= 128 && tid < 128+W4) pfi = kblen[(size_t)(j-1)*W4 + (tid-128)];
    }

    // ---- wait for full h(j-1), load it ----
    if (j > 0){
      const int jm = j - 1, l = tid & 63;
      while (1){
        int v0 = __hip_atomic_load(&flagC[l],    __ATOMIC_ACQUIRE, __HIP_MEMORY_SCOPE_AGENT);
        int v1 = __hip_atomic_load(&flagC[l+64], __ATOMIC_ACQUIRE, __HIP_MEMORY_SCOPE_AGENT);
        if (__all(v0 >= jm && v1 >= jm)) break;
        __builtin_amdgcn_s_sleep(1);
      }
      fence_agent();
      for (int i = tid; i < H; i += NTH)
        S.h_l[i] = ld_acq(&hbuf[i]);
    }
    // commit prefetches to LDS
    S.x_l[tid] = xv0; S.x_l[NTH + tid] = xv1;
    if (j > 0){
      #pragma unroll
      for (int r = 0; r < 8; ++r){
        int i = r*NTH + tid;
        S.we_l[(i >> 9)*520 + (i & 511)] = wv[r];
      }
      if (tid >= 128 && tid < 128+W4) S.klen_l[tid-128] = pfi;
    }
    __syncthreads();

    // ---- PROJ: gx(j)=x·Wi, awi(j)=x·Ai, wgp(j-1)=wemb·Wwi  (64 dots, 2 passes) ----
    {
      const int sub = tid & 7;
      #pragma unroll
      for (int p = 0; p < 2; ++p){
        int dotid = p*32 + (tid >> 3);
        const float* Apt; const float* Wb; int row;
        if (dotid < 12)      { Apt = S.x_l; Wb = S.Wi_l; row = dotid; }
        else if (dotid < 16) { Apt = S.x_l; Wb = S.Ai_l; row = dotid - 12; }
        else { int q = dotid - 16; Apt = &S.we_l[(q/12)*520]; Wb = S.Wwi_l; row = q % 12; }
        float acc = 0.f;
        #pragma unroll
        for (int i2 = 0; i2 < 16; ++i2){
          int cch = (sub << 4) | i2;
          const float4 a4 = *(const float4*)&Apt[cch << 2];
          const float4 w4 = *(const float4*)&Wb[(row << 9) + ((cch ^ (row & 7)) << 2)];
          acc = fmaf(a4.x, w4.x, acc);
          acc = fmaf(a4.y, w4.y, acc);
          acc = fmaf(a4.z, w4.z, acc);
          acc = fmaf(a4.w, w4.w, acc);
        }
        acc += __shfl_xor(acc, 1); acc += __shfl_xor(acc, 2); acc += __shfl_xor(acc, 4);
        if (sub == 0){
          if (dotid < 12)      S.gx_l[dotid]      = acc + S.bmi_l[dotid];
          else if (dotid < 16) S.awi_l[dotid-12]  = acc + S.bal_l[dotid-12];
          else { int q = dotid-16; S.wgp_l[q/12][q%12] = acc + S.bw_l[q%12]; }
        }
      }
      // ---- Phase A: gh(j) = h·Wh cols, wgh(j-1) = h·Wwh cols ----
      if (tid < 192){
        int d = tid >> 3;
        int dd = (d < 12) ? d : (d - 12);
        const float* Wp = (d < 12) ? S.Wh_l : S.Wwh_l;
        float acc = 0.f;
        #pragma unroll
        for (int i2 = 0; i2 < 16; ++i2){
          int cch = (sub << 4) | i2;
          const float4 hv = *(const float4*)&S.h_l[cch << 2];
          const float4 wv4 = *(const float4*)&Wp[(dd << 9) + ((cch ^ (dd & 7)) << 2)];
          acc = fmaf(hv.x, wv4.x, acc);
          acc = fmaf(hv.y, wv4.y, acc);
          acc = fmaf(hv.z, wv4.z, acc);
          acc = fmaf(hv.w, wv4.w, acc);
        }
        acc += __shfl_xor(acc, 1); acc += __shfl_xor(acc, 2); acc += __shfl_xor(acc, 4);
        if (sub == 0){ if (d < 12) S.gh_l[d] = acc; else S.wgh_l[d-12] = acc; }
      }
    }
    __syncthreads();

    if (j > 0){
      // ---- wc(j-1) local slice, publish ----
      if (tid < W4*HS){
        int w = tid >> 2, e = tid & 3;
        float fr = S.wgp_l[w][e]   + S.wgh_l[e];
        float ir = S.wgp_l[w][4+e] + S.wgh_l[4+e];
        float gr = S.wgp_l[w][8+e] + S.wgh_l[8+e];
        float wcv = sigf(fr)*S.c_prev_l[e] + sigf(ir)*tanhft(gr);
        st_rel(&wcbuf[w*H + base + e], wcv);
      }
      fence_agent();
      __syncthreads();
      if (tid == 0) __hip_atomic_store(&flagA[wg], j, __ATOMIC_SEQ_CST, __HIP_MEMORY_SCOPE_AGENT);
      {
        const int l = tid & 63;
        while (1){
          int v0 = __hip_atomic_load(&flagA[l],    __ATOMIC_ACQUIRE, __HIP_MEMORY_SCOPE_AGENT);
          int v1 = __hip_atomic_load(&flagA[l+64], __ATOMIC_ACQUIRE, __HIP_MEMORY_SCOPE_AGENT);
          if (__all(v0 >= j && v1 >= j)) break;
          __builtin_amdgcn_s_sleep(1);
        }
      }
      fence_agent();
      for (int i = tid; i < W4*H; i += NTH){
        int w = i >> 9, k = i & 511;
        S.wcf[w*520 + k] = ld_acq(&wcbuf[i]);
      }
    }
    __syncthreads();

    // ---- Phase B: awh(j-1) slice = wc·Ah cols; ring update ----
    if (j > 0){
      const int s = (j-1) & 7;
      if (tid < 128){
        int dt = tid >> 3, sub = tid & 7;
        int w = dt >> 2, c = dt & 3;
        float acc = 0.f;
        #pragma unroll
        for (int i2 = 0; i2 < 16; ++i2){
          int cch = (sub << 4) | i2;
          const float4 wv4 = *(const float4*)&S.wcf[w*520 + (cch << 2)];
          const float4 av = *(const float4*)&S.Ah_l[(c << 9) + ((cch ^ (c & 7)) << 2)];
          acc = fmaf(wv4.x, av.x, acc);
          acc = fmaf(wv4.y, av.y, acc);
          acc = fmaf(wv4.z, av.z, acc);
          acc = fmaf(wv4.w, av.w, acc);
        }
        acc += __shfl_xor(acc, 1); acc += __shfl_xor(acc, 2); acc += __shfl_xor(acc, 4);
        if (sub == 0) S.ring_awh_l[s][w][c] = acc;
      }
      if (tid < W4*HS){ int w = tid >> 2, e = tid & 3; S.ring_c_l[s][w][e] = S.wcf[w*520 + base + e]; }
      if (tid < W4) S.ring_len_l[s][tid] = S.klen_l[tid];
      if (tid == 0) S.ring_step_l[s] = j-1;
    }
    __syncthreads();

    // ---- Phase C: part2(j) — fully local ----
    if (tid < 128){
      int entry = tid & 31, e = tid >> 5;
      int s = entry >> 2, w = entry & 3;
      bool msk = (S.ring_step_l[s] + S.ring_len_l[s][w] - 1 == j);
      float aw = S.awi_l[e] + S.ring_awh_l[s][w][e];
      float ev  = msk ? __expf(sigf(aw)) : 0.f;
      float ecv = msk ? ev * S.ring_c_l[s][w][e] : 0.f;
      #pragma unroll
      for (int m = 1; m < 32; m <<= 1){
        ev  += __shfl_xor(ev,  m);
        ecv += __shfl_xor(ecv, m);
      }
      int anym = __any((int)msk);
      float ir  = S.gx_l[e]   + S.gh_l[e];
      float orr = S.gx_l[4+e] + S.gh_l[4+e];
      float gr  = S.gx_l[8+e] + S.gh_l[8+e];
      float i_g = sigf(ir), o_g = tanhft(orr), g_g = sigf(gr);
      float e_i = __expf(i_g);
      float c_new;
      if (anym) c_new = (e_i*g_g + ecv) / (e_i + ev);
      else      c_new = (1.f - i_g)*S.c_prev_l[e] + i_g*g_g;
      float h_new = o_g * tanhft(c_new);
      if (entry == 0){
        st_rel(&hbuf[base+e], h_new);
        out[(size_t)j*H + base + e]               = h_new;   // f32 store
        out[(size_t)T*H + (size_t)j*H + base + e] = c_new;   // f32 store
        S.c_prev_l[e] = c_new;
      }
    }
    fence_agent();
    __syncthreads();
    if (tid == 0) __hip_atomic_store(&flagC[wg], j, __ATOMIC_SEQ_CST, __HIP_MEMORY_SCOPE_AGENT);
  }
}

// ---------- launcher ----------
extern "C" void kernel_launch(void* const* d_in, const int* in_sizes, int n_in,
                              void* d_out, int out_size, void* d_ws, size_t ws_size,
                              hipStream_t stream)
{
  const float* x    = (const float*)d_in[0];
  const float* kbe  = (const float*)d_in[1];
  const int*   kblen= (const int*)d_in[2];
  const float* Wi   = (const float*)d_in[3];
  const float* Wh   = (const float*)d_in[4];
  const float* bmi  = (const float*)d_in[5];
  const float* Ai   = (const float*)d_in[6];
  const float* Ah   = (const float*)d_in[7];
  const float* bal  = (const float*)d_in[8];
  const float* Wwi  = (const float*)d_in[9];
  const float* Wwh  = (const float*)d_in[10];
  const float* bw   = (const float*)d_in[11];
  const int T = in_sizes[0] / H;     // 1024
  float* out = (float*)d_out;        // reference output dtype = float32

  // tiny workspace: hbuf[512] | wcbuf[2048] | flagA[128] | flagC[128]
  float* ws    = (float*)d_ws;
  float* hbuf  = ws;
  float* wcbuf = hbuf + 512;
  int*   flagA = (int*)(wcbuf + 2048);
  int*   flagC = flagA + NWG;

  (void)hipMemsetAsync(flagA, 0xFF, 2*NWG*sizeof(int), stream);   // flags = -1

  lattice_serial<<<NWG, NTH, 0, stream>>>(x, kbe, kblen, Wi, Wh, bmi, Ai, Ah, bal,
                                          Wwi, Wwh, bw, hbuf, wcbuf, flagA, flagC, out, T);
}

// Round 12
// 28276.288 us; speedup vs baseline: 3.8469x; 3.8469x over previous
//
#include <hip/hip_runtime.h>

#define H 512
#define W4 4
#define RINGN 8
#define NWG 128
#define HS 4          // H / NWG
#define NTH 256

// ---------- helpers ----------
__device__ __forceinline__ float sigf(float x){ return 1.f/(1.f+__expf(-x)); }
__device__ __forceinline__ float tanhft(float x){
  float t = __expf(-2.f*fabsf(x));      // never overflows
  float r = (1.f - t)/(1.f + t);
  return copysignf(r, x);
}
// swizzled LDS element index for column-major weight slices
__device__ __forceinline__ int swz(int dd, int k){
  return (dd << 9) | ((((k >> 2) ^ (dd & 7)) << 2) | (k & 3));
}
__device__ __forceinline__ void st_rel(float* p, float v){
  __hip_atomic_store(p, v, __ATOMIC_RELEASE, __HIP_MEMORY_SCOPE_AGENT);
}
__device__ __forceinline__ unsigned long long ld_rel8(const unsigned long long* p){
  return __hip_atomic_load(p, __ATOMIC_RELAXED, __HIP_MEMORY_SCOPE_AGENT);
}

// wave-0-only spin on 128 flags; others park at barrier. Acquire + fence by wave 0.
__device__ __forceinline__ void spin_flags(int* flags, int target, int tid){
  if (tid < 64){
    while (1){
      int v0 = __hip_atomic_load(&flags[tid],      __ATOMIC_ACQUIRE, __HIP_MEMORY_SCOPE_AGENT);
      int v1 = __hip_atomic_load(&flags[tid + 64], __ATOMIC_ACQUIRE, __HIP_MEMORY_SCOPE_AGENT);
      if (__all(v0 >= target && v1 >= target)) break;
      __builtin_amdgcn_s_sleep(1);
    }
    __threadfence();
  }
  __syncthreads();
}

// ---------- persistent serial lattice scan (all projections in-kernel) ----------
struct SLds {
  float Wh_l [12*512];
  float Wwh_l[12*512];
  float Wi_l [12*512];
  float Wwi_l[12*512];
  float Ah_l [4*512];
  float Ai_l [4*512];
  float h_l [H];
  float x_l [H];
  float we_l[W4*520];          // wemb(j-1) rows, padded stride
  float wcf [W4*520];          // full wc(j-1), padded stride
  float gh_l[12];
  float wgh_l[12];
  float gx_l[12];
  float awi_l[HS];
  float wgp_l[W4][12];
  float bmi_l[12];
  float bw_l [12];
  float bal_l[HS];
  float ring_c_l  [RINGN][W4][HS];
  float ring_awh_l[RINGN][W4][HS];
  float c_prev_l[HS];
  int ring_len_l[RINGN][W4];
  int ring_step_l[RINGN];
  int klen_l[W4];
};

__global__ __launch_bounds__(NTH) void lattice_serial(
    const float* __restrict__ xg,  const float* __restrict__ kbe,
    const int*   __restrict__ kblen,
    const float* __restrict__ Wi,  const float* __restrict__ Wh,
    const float* __restrict__ bmi, const float* __restrict__ Ai,
    const float* __restrict__ Ah,  const float* __restrict__ bal,
    const float* __restrict__ Wwi, const float* __restrict__ Wwh,
    const float* __restrict__ bw,
    float* hbuf, float* wcbuf, int* flagA, int* flagC,
    float* __restrict__ out, int T)
{
  __shared__ SLds S;
  const int tid  = threadIdx.x;
  const int wg   = blockIdx.x;
  const int base = wg * HS;

  // ---- stage weight column slices (f32, swizzled) ----
  for (int i = tid; i < 12*512; i += NTH){
    int d = i >> 9, k = i & 511;
    size_t gcol = (size_t)(d >> 2)*512 + base + (d & 3);
    S.Wh_l [swz(d,k)] = Wh [(size_t)k*1536 + gcol];
    S.Wwh_l[swz(d,k)] = Wwh[(size_t)k*1536 + gcol];
    S.Wi_l [swz(d,k)] = Wi [(size_t)k*1536 + gcol];
    S.Wwi_l[swz(d,k)] = Wwi[(size_t)k*1536 + gcol];
  }
  for (int i = tid; i < 4*512; i += NTH){
    int c = i >> 9, k = i & 511;
    S.Ah_l[swz(c,k)] = Ah[(size_t)k*512 + base + c];
    S.Ai_l[swz(c,k)] = Ai[(size_t)k*512 + base + c];
  }
  if (tid < 12){
    int gcol = (tid >> 2)*512 + base + (tid & 3);
    S.bmi_l[tid] = bmi[gcol];
    S.bw_l [tid] = bw [gcol];
  }
  if (tid >= 16 && tid < 16+HS) S.bal_l[tid-16] = bal[base + tid - 16];
  for (int i = tid; i < H; i += NTH){ S.h_l[i] = 0.f; S.x_l[i] = 0.f; }
  for (int i = tid; i < W4*520; i += NTH) S.we_l[i] = 0.f;
  for (int i = tid; i < RINGN*W4*HS; i += NTH){
    ((float*)S.ring_c_l)[i]   = 0.f;
    ((float*)S.ring_awh_l)[i] = 0.f;
  }
  if (tid < RINGN) S.ring_step_l[tid] = -2*RINGN;
  if (tid < RINGN*W4) ((int*)S.ring_len_l)[tid] = 0;
  if (tid < HS) S.c_prev_l[tid] = 0.f;
  __syncthreads();

  for (int j = 0; j < T; ++j){
    // ---- prefetch x(j), wemb(j-1), klen(j-1); commit to LDS (flag-independent) ----
    {
      float xv0 = xg[(size_t)j*H + tid];
      float xv1 = xg[(size_t)j*H + NTH + tid];
      S.x_l[tid] = xv0; S.x_l[NTH + tid] = xv1;
      if (j > 0){
        #pragma unroll
        for (int r = 0; r < 8; ++r){
          int i = r*NTH + tid;
          S.we_l[(i >> 9)*520 + (i & 511)] = kbe[(size_t)(j-1)*(W4*H) + i];
        }
        if (tid < W4) S.klen_l[tid] = kblen[(size_t)(j-1)*W4 + tid];
      }
    }

    // ---- wait for full h(j-1); wide relaxed loads ----
    if (j > 0){
      spin_flags(flagC, j-1, tid);
      unsigned long long v = ld_rel8((const unsigned long long*)hbuf + tid);  // 256 x 8B = H
      ((unsigned long long*)S.h_l)[tid] = v;
    }
    __syncthreads();

    // ---- PROJ: gx(j)=x·Wi, awi(j)=x·Ai, wgp(j-1)=wemb·Wwi  (64 dots, 2 passes) ----
    {
      const int sub = tid & 7;
      #pragma unroll
      for (int p = 0; p < 2; ++p){
        int dotid = p*32 + (tid >> 3);
        const float* Apt; const float* Wb; int row;
        if (dotid < 12)      { Apt = S.x_l; Wb = S.Wi_l; row = dotid; }
        else if (dotid < 16) { Apt = S.x_l; Wb = S.Ai_l; row = dotid - 12; }
        else { int q = dotid - 16; Apt = &S.we_l[(q/12)*520]; Wb = S.Wwi_l; row = q % 12; }
        float acc = 0.f;
        #pragma unroll
        for (int i2 = 0; i2 < 16; ++i2){
          int cch = (i2 << 3) | sub;                 // consecutive chunks per 8-lane group
          const float4 a4 = *(const float4*)&Apt[cch << 2];
          const float4 w4 = *(const float4*)&Wb[(row << 9) + ((cch ^ (row & 7)) << 2)];
          acc = fmaf(a4.x, w4.x, acc);
          acc = fmaf(a4.y, w4.y, acc);
          acc = fmaf(a4.z, w4.z, acc);
          acc = fmaf(a4.w, w4.w, acc);
        }
        acc += __shfl_xor(acc, 1); acc += __shfl_xor(acc, 2); acc += __shfl_xor(acc, 4);
        if (sub == 0){
          if (dotid < 12)      S.gx_l[dotid]      = acc + S.bmi_l[dotid];
          else if (dotid < 16) S.awi_l[dotid-12]  = acc + S.bal_l[dotid-12];
          else { int q = dotid-16; S.wgp_l[q/12][q%12] = acc + S.bw_l[q%12]; }
        }
      }
      // ---- Phase A: gh(j) = h·Wh cols, wgh(j-1) = h·Wwh cols ----
      if (tid < 192){
        int d = tid >> 3;
        int dd = (d < 12) ? d : (d - 12);
        const float* Wp = (d < 12) ? S.Wh_l : S.Wwh_l;
        float acc = 0.f;
        #pragma unroll
        for (int i2 = 0; i2 < 16; ++i2){
          int cch = (i2 << 3) | sub;
          const float4 hv  = *(const float4*)&S.h_l[cch << 2];
          const float4 wv4 = *(const float4*)&Wp[(dd << 9) + ((cch ^ (dd & 7)) << 2)];
          acc = fmaf(hv.x, wv4.x, acc);
          acc = fmaf(hv.y, wv4.y, acc);
          acc = fmaf(hv.z, wv4.z, acc);
          acc = fmaf(hv.w, wv4.w, acc);
        }
        acc += __shfl_xor(acc, 1); acc += __shfl_xor(acc, 2); acc += __shfl_xor(acc, 4);
        if (sub == 0){ if (d < 12) S.gh_l[d] = acc; else S.wgh_l[d-12] = acc; }
      }
    }
    __syncthreads();

    if (j > 0){
      // ---- wc(j-1) local slice, publish (release stores + writer fence) ----
      if (tid < W4*HS){
        int w = tid >> 2, e = tid & 3;
        float fr = S.wgp_l[w][e]   + S.wgh_l[e];
        float ir = S.wgp_l[w][4+e] + S.wgh_l[4+e];
        float gr = S.wgp_l[w][8+e] + S.wgh_l[8+e];
        float wcv = sigf(fr)*S.c_prev_l[e] + sigf(ir)*tanhft(gr);
        st_rel(&wcbuf[w*H + base + e], wcv);
        __threadfence();
      }
      __syncthreads();
      if (tid == 0) __hip_atomic_store(&flagA[wg], j, __ATOMIC_SEQ_CST, __HIP_MEMORY_SCOPE_AGENT);
      spin_flags(flagA, j, tid);
      // ---- wide relaxed load of full wc(j-1) ----
      {
        const unsigned long long* wb = (const unsigned long long*)wcbuf;
        #pragma unroll
        for (int r = 0; r < 4; ++r){
          int i = r*NTH + tid;                       // pair index 0..1023
          unsigned long long v = ld_rel8(&wb[i]);
          int w = i >> 8, k = (i & 255) << 1;
          *(unsigned long long*)&S.wcf[w*520 + k] = v;
        }
      }
    }
    __syncthreads();

    // ---- Phase B: awh(j-1) slice = wc·Ah cols; ring update ----
    if (j > 0){
      const int s = (j-1) & 7;
      if (tid < 128){
        int dt = tid >> 3, sub = tid & 7;
        int w = dt >> 2, c = dt & 3;
        float acc = 0.f;
        #pragma unroll
        for (int i2 = 0; i2 < 16; ++i2){
          int cch = (i2 << 3) | sub;
          const float4 wv4 = *(const float4*)&S.wcf[w*520 + (cch << 2)];
          const float4 av  = *(const float4*)&S.Ah_l[(c << 9) + ((cch ^ (c & 7)) << 2)];
          acc = fmaf(wv4.x, av.x, acc);
          acc = fmaf(wv4.y, av.y, acc);
          acc = fmaf(wv4.z, av.z, acc);
          acc = fmaf(wv4.w, av.w, acc);
        }
        acc += __shfl_xor(acc, 1); acc += __shfl_xor(acc, 2); acc += __shfl_xor(acc, 4);
        if (sub == 0) S.ring_awh_l[s][w][c] = acc;
      }
      if (tid < W4*HS){ int w = tid >> 2, e = tid & 3; S.ring_c_l[s][w][e] = S.wcf[w*520 + base + e]; }
      if (tid < W4) S.ring_len_l[s][tid] = S.klen_l[tid];
      if (tid == 0) S.ring_step_l[s] = j-1;
    }
    __syncthreads();

    // ---- Phase C: part2(j) — fully local ----
    if (tid < 128){
      int entry = tid & 31, e = tid >> 5;
      int s = entry >> 2, w = entry & 3;
      bool msk = (S.ring_step_l[s] + S.ring_len_l[s][w] - 1 == j);
      float aw = S.awi_l[e] + S.ring_awh_l[s][w][e];
      float ev  = msk ? __expf(sigf(aw)) : 0.f;
      float ecv = msk ? ev * S.ring_c_l[s][w][e] : 0.f;
      #pragma unroll
      for (int m = 1; m < 32; m <<= 1){
        ev  += __shfl_xor(ev,  m);
        ecv += __shfl_xor(ecv, m);
      }
      int anym = __any((int)msk);
      float ir  = S.gx_l[e]   + S.gh_l[e];
      float orr = S.gx_l[4+e] + S.gh_l[4+e];
      float gr  = S.gx_l[8+e] + S.gh_l[8+e];
      float i_g = sigf(ir), o_g = tanhft(orr), g_g = sigf(gr);
      float e_i = __expf(i_g);
      float c_new;
      if (anym) c_new = (e_i*g_g + ecv) / (e_i + ev);
      else      c_new = (1.f - i_g)*S.c_prev_l[e] + i_g*g_g;
      float h_new = o_g * tanhft(c_new);
      if (entry == 0){
        st_rel(&hbuf[base+e], h_new);
        out[(size_t)j*H + base + e]               = h_new;   // f32 store
        out[(size_t)T*H + (size_t)j*H + base + e] = c_new;   // f32 store
        S.c_prev_l[e] = c_new;
        __threadfence();
      }
    }
    __syncthreads();
    if (tid == 0) __hip_atomic_store(&flagC[wg], j, __ATOMIC_SEQ_CST, __HIP_MEMORY_SCOPE_AGENT);
  }
}

// ---------- launcher ----------
extern "C" void kernel_launch(void* const* d_in, const int* in_sizes, int n_in,
                              void* d_out, int out_size, void* d_ws, size_t ws_size,
                              hipStream_t stream)
{
  const float* x    = (const float*)d_in[0];
  const float* kbe  = (const float*)d_in[1];
  const int*   kblen= (const int*)d_in[2];
  const float* Wi   = (const float*)d_in[3];
  const float* Wh   = (const float*)d_in[4];
  const float* bmi  = (const float*)d_in[5];
  const float* Ai   = (const float*)d_in[6];
  const float* Ah   = (const float*)d_in[7];
  const float* bal  = (const float*)d_in[8];
  const float* Wwi  = (const float*)d_in[9];
  const float* Wwh  = (const float*)d_in[10];
  const float* bw   = (const float*)d_in[11];
  const int T = in_sizes[0] / H;     // 1024
  float* out = (float*)d_out;        // reference output dtype = float32

  // tiny workspace: hbuf[512] | wcbuf[2048] | flagA[128] | flagC[128]
  float* ws    = (float*)d_ws;
  float* hbuf  = ws;
  float* wcbuf = hbuf + 512;
  int*   flagA = (int*)(wcbuf + 2048);
  int*   flagC = flagA + NWG;

  (void)hipMemsetAsync(flagA, 0xFF, 2*NWG*sizeof(int), stream);   // flags = -1

  lattice_serial<<<NWG, NTH, 0, stream>>>(x, kbe, kblen, Wi, Wh, bmi, Ai, Ah, bal,
                                          Wwi, Wwh, bw, hbuf, wcbuf, flagA, flagC, out, T);
}

// Round 13
// 15132.880 us; speedup vs baseline: 7.1881x; 1.8685x over previous
//
#include <hip/hip_runtime.h>

#define H 512
#define W4 4
#define RINGN 8
#define NWG 128
#define HS 4          // H / NWG
#define NTH 256

// ---------- helpers ----------
__device__ __forceinline__ float sigf(float x){ return 1.f/(1.f+__expf(-x)); }
__device__ __forceinline__ float tanhft(float x){
  float t = __expf(-2.f*fabsf(x));      // never overflows
  float r = (1.f - t)/(1.f + t);
  return copysignf(r, x);
}
// swizzled LDS element index for column-major weight slices
__device__ __forceinline__ int swz(int dd, int k){
  return (dd << 9) | ((((k >> 2) ^ (dd & 7)) << 2) | (k & 3));
}
__device__ __forceinline__ void st_relax(float* p, float v){
  __hip_atomic_store(p, v, __ATOMIC_RELAXED, __HIP_MEMORY_SCOPE_AGENT);
}
__device__ __forceinline__ unsigned long long ld_relax8(const unsigned long long* p){
  return __hip_atomic_load(p, __ATOMIC_RELAXED, __HIP_MEMORY_SCOPE_AGENT);
}

// grid barrier: counter arrival + single-lane poll (one cacheline of spin traffic).
// __syncthreads drains vmcnt -> all WG stores IC-visible before the arrival RMW.
__device__ __forceinline__ void xbar(int* c, int tid){
  __syncthreads();
  if (tid == 0){
    __hip_atomic_fetch_add(c, 1, __ATOMIC_ACQ_REL, __HIP_MEMORY_SCOPE_AGENT);
    while (__hip_atomic_load(c, __ATOMIC_ACQUIRE, __HIP_MEMORY_SCOPE_AGENT) < NWG)
      __builtin_amdgcn_s_sleep(2);
  }
  __syncthreads();
}

// ---------- persistent serial lattice scan (all projections in-kernel) ----------
struct SLds {
  float Wh_l [12*512];
  float Wwh_l[12*512];
  float Wi_l [12*512];
  float Wwi_l[12*512];
  float Ah_l [4*512];
  float Ai_l [4*512];
  float h_l [H];
  float x_l [H];
  float we_l[W4*520];          // wemb(j-1) rows, padded stride
  float wcf [W4*520];          // full wc(j-1), padded stride
  float gh_l[12];
  float wgh_l[12];
  float gx_l[12];
  float awi_l[HS];
  float wgp_l[W4][12];
  float bmi_l[12];
  float bw_l [12];
  float bal_l[HS];
  float ring_c_l  [RINGN][W4][HS];
  float ring_awh_l[RINGN][W4][HS];
  float c_prev_l[HS];
  int ring_len_l[RINGN][W4];
  int ring_step_l[RINGN];
  int klen_l[W4];
};

__global__ __launch_bounds__(NTH) void lattice_serial(
    const float* __restrict__ xg,  const float* __restrict__ kbe,
    const int*   __restrict__ kblen,
    const float* __restrict__ Wi,  const float* __restrict__ Wh,
    const float* __restrict__ bmi, const float* __restrict__ Ai,
    const float* __restrict__ Ah,  const float* __restrict__ bal,
    const float* __restrict__ Wwi, const float* __restrict__ Wwh,
    const float* __restrict__ bw,
    float* hbuf, float* wcbuf, int* cnt,
    float* __restrict__ out, int T)
{
  __shared__ SLds S;
  const int tid  = threadIdx.x;
  const int wg   = blockIdx.x;
  const int base = wg * HS;

  // ---- stage weight column slices (f32, swizzled) ----
  for (int i = tid; i < 12*512; i += NTH){
    int d = i >> 9, k = i & 511;
    size_t gcol = (size_t)(d >> 2)*512 + base + (d & 3);
    S.Wh_l [swz(d,k)] = Wh [(size_t)k*1536 + gcol];
    S.Wwh_l[swz(d,k)] = Wwh[(size_t)k*1536 + gcol];
    S.Wi_l [swz(d,k)] = Wi [(size_t)k*1536 + gcol];
    S.Wwi_l[swz(d,k)] = Wwi[(size_t)k*1536 + gcol];
  }
  for (int i = tid; i < 4*512; i += NTH){
    int c = i >> 9, k = i & 511;
    S.Ah_l[swz(c,k)] = Ah[(size_t)k*512 + base + c];
    S.Ai_l[swz(c,k)] = Ai[(size_t)k*512 + base + c];
  }
  if (tid < 12){
    int gcol = (tid >> 2)*512 + base + (tid & 3);
    S.bmi_l[tid] = bmi[gcol];
    S.bw_l [tid] = bw [gcol];
  }
  if (tid >= 16 && tid < 16+HS) S.bal_l[tid-16] = bal[base + tid - 16];
  for (int i = tid; i < H; i += NTH){ S.h_l[i] = 0.f; S.x_l[i] = 0.f; }
  for (int i = tid; i < W4*520; i += NTH) S.we_l[i] = 0.f;
  for (int i = tid; i < RINGN*W4*HS; i += NTH){
    ((float*)S.ring_c_l)[i]   = 0.f;
    ((float*)S.ring_awh_l)[i] = 0.f;
  }
  if (tid < RINGN) S.ring_step_l[tid] = -2*RINGN;
  if (tid < RINGN*W4) ((int*)S.ring_len_l)[tid] = 0;
  if (tid < HS) S.c_prev_l[tid] = 0.f;
  __syncthreads();

  for (int j = 0; j < T; ++j){
    // ---- stage x(j), wemb(j-1), klen(j-1) into LDS (no h dependency) ----
    {
      float xv0 = xg[(size_t)j*H + tid];
      float xv1 = xg[(size_t)j*H + NTH + tid];
      S.x_l[tid] = xv0; S.x_l[NTH + tid] = xv1;
      if (j > 0){
        #pragma unroll
        for (int r = 0; r < 8; ++r){
          int i = r*NTH + tid;
          S.we_l[(i >> 9)*520 + (i & 511)] = kbe[(size_t)(j-1)*(W4*H) + i];
        }
        if (tid < W4) S.klen_l[tid] = kblen[(size_t)(j-1)*W4 + tid];
      }
    }
    __syncthreads();

    // ---- PROJ (h-independent, hidden off the serial chain):
    //      gx(j)=x·Wi, awi(j)=x·Ai, wgp(j-1)=wemb·Wwi  (64 dots, 2 passes) ----
    {
      const int sub = tid & 7;
      #pragma unroll
      for (int p = 0; p < 2; ++p){
        int dotid = p*32 + (tid >> 3);
        const float* Apt; const float* Wb; int row;
        if (dotid < 12)      { Apt = S.x_l; Wb = S.Wi_l; row = dotid; }
        else if (dotid < 16) { Apt = S.x_l; Wb = S.Ai_l; row = dotid - 12; }
        else { int q = dotid - 16; Apt = &S.we_l[(q/12)*520]; Wb = S.Wwi_l; row = q % 12; }
        float acc = 0.f;
        #pragma unroll
        for (int i2 = 0; i2 < 16; ++i2){
          int cch = (i2 << 3) | sub;                 // consecutive chunks per 8-lane group
          const float4 a4 = *(const float4*)&Apt[cch << 2];
          const float4 w4 = *(const float4*)&Wb[(row << 9) + ((cch ^ (row & 7)) << 2)];
          acc = fmaf(a4.x, w4.x, acc);
          acc = fmaf(a4.y, w4.y, acc);
          acc = fmaf(a4.z, w4.z, acc);
          acc = fmaf(a4.w, w4.w, acc);
        }
        acc += __shfl_xor(acc, 1); acc += __shfl_xor(acc, 2); acc += __shfl_xor(acc, 4);
        if (sub == 0){
          if (dotid < 12)      S.gx_l[dotid]      = acc + S.bmi_l[dotid];
          else if (dotid < 16) S.awi_l[dotid-12]  = acc + S.bal_l[dotid-12];
          else { int q = dotid-16; S.wgp_l[q/12][q%12] = acc + S.bw_l[q%12]; }
        }
      }
    }

    // ---- read h(j-1): grid-synced at end of step j-1; wide relaxed IC loads ----
    if (j > 0){
      unsigned long long v = ld_relax8((const unsigned long long*)hbuf + tid);  // 256 x 8B = H
      ((unsigned long long*)S.h_l)[tid] = v;
    }
    __syncthreads();

    // ---- Phase A: gh(j) = h·Wh cols, wgh(j-1) = h·Wwh cols ----
    if (tid < 192){
      const int sub = tid & 7;
      int d = tid >> 3;
      int dd = (d < 12) ? d : (d - 12);
      const float* Wp = (d < 12) ? S.Wh_l : S.Wwh_l;
      float acc = 0.f;
      #pragma unroll
      for (int i2 = 0; i2 < 16; ++i2){
        int cch = (i2 << 3) | sub;
        const float4 hv  = *(const float4*)&S.h_l[cch << 2];
        const float4 wv4 = *(const float4*)&Wp[(dd << 9) + ((cch ^ (dd & 7)) << 2)];
        acc = fmaf(hv.x, wv4.x, acc);
        acc = fmaf(hv.y, wv4.y, acc);
        acc = fmaf(hv.z, wv4.z, acc);
        acc = fmaf(hv.w, wv4.w, acc);
      }
      acc += __shfl_xor(acc, 1); acc += __shfl_xor(acc, 2); acc += __shfl_xor(acc, 4);
      if (sub == 0){ if (d < 12) S.gh_l[d] = acc; else S.wgh_l[d-12] = acc; }
    }
    __syncthreads();

    if (j > 0){
      // ---- wc(j-1) local slice, publish (relaxed IC stores; xbar drains) ----
      if (tid < W4*HS){
        int w = tid >> 2, e = tid & 3;
        float fr = S.wgp_l[w][e]   + S.wgh_l[e];
        float ir = S.wgp_l[w][4+e] + S.wgh_l[4+e];
        float gr = S.wgp_l[w][8+e] + S.wgh_l[8+e];
        float wcv = sigf(fr)*S.c_prev_l[e] + sigf(ir)*tanhft(gr);
        st_relax(&wcbuf[w*H + base + e], wcv);
      }
      xbar(&cnt[2*j], tid);
      // ---- wide relaxed load of full wc(j-1) ----
      {
        const unsigned long long* wb = (const unsigned long long*)wcbuf;
        #pragma unroll
        for (int r = 0; r < 4; ++r){
          int i = r*NTH + tid;                       // pair index 0..1023
          unsigned long long v = ld_relax8(&wb[i]);
          int w = i >> 8, k = (i & 255) << 1;
          *(unsigned long long*)&S.wcf[w*520 + k] = v;
        }
      }
    }
    __syncthreads();

    // ---- Phase B: awh(j-1) slice = wc·Ah cols; ring update ----
    if (j > 0){
      const int s = (j-1) & 7;
      if (tid < 128){
        int dt = tid >> 3, sub = tid & 7;
        int w = dt >> 2, c = dt & 3;
        float acc = 0.f;
        #pragma unroll
        for (int i2 = 0; i2 < 16; ++i2){
          int cch = (i2 << 3) | sub;
          const float4 wv4 = *(const float4*)&S.wcf[w*520 + (cch << 2)];
          const float4 av  = *(const float4*)&S.Ah_l[(c << 9) + ((cch ^ (c & 7)) << 2)];
          acc = fmaf(wv4.x, av.x, acc);
          acc = fmaf(wv4.y, av.y, acc);
          acc = fmaf(wv4.z, av.z, acc);
          acc = fmaf(wv4.w, av.w, acc);
        }
        acc += __shfl_xor(acc, 1); acc += __shfl_xor(acc, 2); acc += __shfl_xor(acc, 4);
        if (sub == 0) S.ring_awh_l[s][w][c] = acc;
      }
      if (tid < W4*HS){ int w = tid >> 2, e = tid & 3; S.ring_c_l[s][w][e] = S.wcf[w*520 + base + e]; }
      if (tid < W4) S.ring_len_l[s][tid] = S.klen_l[tid];
      if (tid == 0) S.ring_step_l[s] = j-1;
    }
    __syncthreads();

    // ---- Phase C: part2(j) — fully local; publish h(j) ----
    if (tid < 128){
      int entry = tid & 31, e = tid >> 5;
      int s = entry >> 2, w = entry & 3;
      bool msk = (S.ring_step_l[s] + S.ring_len_l[s][w] - 1 == j);
      float aw = S.awi_l[e] + S.ring_awh_l[s][w][e];
      float ev  = msk ? __expf(sigf(aw)) : 0.f;
      float ecv = msk ? ev * S.ring_c_l[s][w][e] : 0.f;
      #pragma unroll
      for (int m = 1; m < 32; m <<= 1){
        ev  += __shfl_xor(ev,  m);
        ecv += __shfl_xor(ecv, m);
      }
      int anym = __any((int)msk);
      float ir  = S.gx_l[e]   + S.gh_l[e];
      float orr = S.gx_l[4+e] + S.gh_l[4+e];
      float gr  = S.gx_l[8+e] + S.gh_l[8+e];
      float i_g = sigf(ir), o_g = tanhft(orr), g_g = sigf(gr);
      float e_i = __expf(i_g);
      float c_new;
      if (anym) c_new = (e_i*g_g + ecv) / (e_i + ev);
      else      c_new = (1.f - i_g)*S.c_prev_l[e] + i_g*g_g;
      float h_new = o_g * tanhft(c_new);
      if (entry == 0){
        st_relax(&hbuf[base+e], h_new);
        out[(size_t)j*H + base + e]               = h_new;   // f32 store
        out[(size_t)T*H + (size_t)j*H + base + e] = c_new;   // f32 store
        S.c_prev_l[e] = c_new;
      }
    }
    xbar(&cnt[2*j+1], tid);   // h(j) globally published
  }
}

// ---------- launcher ----------
extern "C" void kernel_launch(void* const* d_in, const int* in_sizes, int n_in,
                              void* d_out, int out_size, void* d_ws, size_t ws_size,
                              hipStream_t stream)
{
  const float* x    = (const float*)d_in[0];
  const float* kbe  = (const float*)d_in[1];
  const int*   kblen= (const int*)d_in[2];
  const float* Wi   = (const float*)d_in[3];
  const float* Wh   = (const float*)d_in[4];
  const float* bmi  = (const float*)d_in[5];
  const float* Ai   = (const float*)d_in[6];
  const float* Ah   = (const float*)d_in[7];
  const float* bal  = (const float*)d_in[8];
  const float* Wwi  = (const float*)d_in[9];
  const float* Wwh  = (const float*)d_in[10];
  const float* bw   = (const float*)d_in[11];
  const int T = in_sizes[0] / H;     // 1024
  float* out = (float*)d_out;        // reference output dtype = float32

  // workspace: hbuf[512] | wcbuf[2048] | cnt[2*T]
  float* ws    = (float*)d_ws;
  float* hbuf  = ws;
  float* wcbuf = hbuf + 512;
  int*   cnt   = (int*)(wcbuf + 2048);

  (void)hipMemsetAsync(cnt, 0, (size_t)2*T*sizeof(int), stream);

  lattice_serial<<<NWG, NTH, 0, stream>>>(x, kbe, kblen, Wi, Wh, bmi, Ai, Ah, bal,
                                          Wwi, Wwh, bw, hbuf, wcbuf, cnt, out, T);
}